// Round 1
// baseline (7984.935 us; speedup 1.0000x reference)
//
#include <hip/hip_runtime.h>

#define EPS 0.01f
#define TSTEPS 2048
#define BATCH 64

typedef __bf16 bf16_t;
typedef bf16_t bf16x8 __attribute__((ext_vector_type(8)));
typedef float f32x4 __attribute__((ext_vector_type(4)));

// ---------------------------------------------------------------------------
// prep_mc: build combined matrix Mc[k][j], row-major [256][512].
//   j <  256 : column j of A = B - 0.6*B^T - 0.01*I
//   j >= 256 : column (j-256) of W = C - 0.6*C^T - 0.01*I
// Scan thread j reads Mc[k*512 + j] (coalesced across j).
// ---------------------------------------------------------------------------
__global__ void prep_mc(const float* __restrict__ Bm, const float* __restrict__ Cm,
                        float* __restrict__ mc) {
    int k = blockIdx.x;   // 256 blocks
    int j = threadIdx.x;  // 256 threads
    float diag = (k == j) ? 0.01f : 0.0f;
    float a = Bm[k * 256 + j] - 0.6f * Bm[j * 256 + k] - diag;
    float w = Cm[k * 256 + j] - 0.6f * Cm[j * 256 + k] - diag;
    mc[k * 512 + j] = a;
    mc[k * 512 + 256 + j] = w;
}

// ---------------------------------------------------------------------------
// pack_u: U (256x256 fp32) -> bf16 B-operand fragment layout for
// mfma_f32_16x16x32_bf16.  Fragment block (kk,nn):
//   up[((kk*16+nn)*64 + lane)*8 + jj] = U[kk*32 + (lane>>4)*8 + jj][nn*16 + (lane&15)]
// ---------------------------------------------------------------------------
__global__ void pack_u(const float* __restrict__ U, bf16_t* __restrict__ up) {
    int t = blockIdx.x * 64 + threadIdx.x;  // 8192 threads: 128 blocks x 64
    int lane = t & 63;
    int tile = t >> 6;      // 0..127 = kk*16 + nn
    int nn = tile & 15;
    int kk = tile >> 4;
    int krow = kk * 32 + (lane >> 4) * 8;
    int col = nn * 16 + (lane & 15);
    long off = (long)t * 8;
#pragma unroll
    for (int jj = 0; jj < 8; ++jj) {
        up[off + jj] = (bf16_t)U[(krow + jj) * 256 + col];
    }
}

// ---------------------------------------------------------------------------
// xu_gemm: out[r][n] = sum_k x[r][k]*U[k][n] + bias[n], r in [0,131072)
// bf16 MFMA 16x16x32. Block = 256 thr (4 waves), each wave does 16 rows x 256
// cols (16 N-tiles, K=256 in 8 steps). A-frag straight from global fp32 + cvt.
// ---------------------------------------------------------------------------
__global__ __launch_bounds__(256) void xu_gemm(const float* __restrict__ x,
                                               const bf16_t* __restrict__ up,
                                               const float* __restrict__ bias,
                                               float* __restrict__ out) {
    int wave = threadIdx.x >> 6;
    int lane = threadIdx.x & 63;
    int m = lane & 15;
    int quad = lane >> 4;
    long row0 = (long)blockIdx.x * 64 + wave * 16;
    const float* xrow = x + (row0 + m) * 256 + quad * 8;

    f32x4 acc[16];
#pragma unroll
    for (int nn = 0; nn < 16; ++nn) acc[nn] = (f32x4){0.f, 0.f, 0.f, 0.f};

#pragma unroll
    for (int kk = 0; kk < 8; ++kk) {
        f32x4 xa = *(const f32x4*)(xrow + kk * 32);
        f32x4 xb = *(const f32x4*)(xrow + kk * 32 + 4);
        bf16x8 af;
        af[0] = (bf16_t)xa[0]; af[1] = (bf16_t)xa[1];
        af[2] = (bf16_t)xa[2]; af[3] = (bf16_t)xa[3];
        af[4] = (bf16_t)xb[0]; af[5] = (bf16_t)xb[1];
        af[6] = (bf16_t)xb[2]; af[7] = (bf16_t)xb[3];
        const bf16_t* ub = up + ((long)kk * 1024 + lane) * 8;
#pragma unroll
        for (int nn = 0; nn < 16; ++nn) {
            bf16x8 bf = *(const bf16x8*)(ub + (long)nn * 512);
            acc[nn] = __builtin_amdgcn_mfma_f32_16x16x32_bf16(af, bf, acc[nn], 0, 0, 0);
        }
    }
    // C/D layout: col = lane&15, row = quad*4 + i
#pragma unroll
    for (int nn = 0; nn < 16; ++nn) {
        int col = nn * 16 + m;
        float bv = bias[col];
#pragma unroll
        for (int i = 0; i < 4; ++i) {
            out[(row0 + quad * 4 + i) * 256 + col] = acc[nn][i] + bv;
        }
    }
}

// ---------------------------------------------------------------------------
// scan_kernel: one workgroup per batch element, 512 threads.
// Thread j holds column j of Mc (256 floats) in VGPRs.
//   j <  256: computes (h@A)[j]
//   j >= 256: computes (h@W)[j-256] + xu[j-256]
// h lives in LDS; xu is read from io (d_out) and overwritten with h_t.
// ---------------------------------------------------------------------------
__global__ __launch_bounds__(512) void scan_kernel(const float* __restrict__ mc,
                                                   float* __restrict__ io) {
    int b = blockIdx.x;   // 64
    int j = threadIdx.x;  // 512

    float mcol[256];
#pragma unroll
    for (int k = 0; k < 256; ++k) mcol[k] = mc[k * 512 + j];

    __shared__ __align__(16) float h[256];
    __shared__ float oa[256];
    __shared__ float ow[256];
    if (j < 256) h[j] = 0.0f;
    float* base = io + (long)b * TSTEPS * 256;
    __syncthreads();

    for (int t = 0; t < TSTEPS; ++t) {
        float xu = 0.0f;
        if (j >= 256) xu = base[t * 256 + (j - 256)];

        float a0 = 0.f, a1 = 0.f, a2 = 0.f, a3 = 0.f;
#pragma unroll
        for (int k = 0; k < 256; k += 4) {
            f32x4 hv = *(const f32x4*)(h + k);   // ds_read_b128 broadcast
            a0 += hv[0] * mcol[k];
            a1 += hv[1] * mcol[k + 1];
            a2 += hv[2] * mcol[k + 2];
            a3 += hv[3] * mcol[k + 3];
        }
        float r = (a0 + a1) + (a2 + a3);

        if (j < 256) oa[j] = r;
        else         ow[j - 256] = r + xu;
        __syncthreads();

        if (j < 256) {
            float hn = h[j] + EPS * oa[j] + EPS * tanhf(ow[j]);
            h[j] = hn;
            base[t * 256 + j] = hn;
        }
        __syncthreads();
    }
}

extern "C" void kernel_launch(void* const* d_in, const int* in_sizes, int n_in,
                              void* d_out, int out_size, void* d_ws, size_t ws_size,
                              hipStream_t stream) {
    const float* x    = (const float*)d_in[0];
    const float* C    = (const float*)d_in[1];
    const float* Bm   = (const float*)d_in[2];
    const float* U    = (const float*)d_in[3];
    const float* bias = (const float*)d_in[4];
    float* out = (float*)d_out;

    float* mc  = (float*)d_ws;                                // 512 KB
    bf16_t* up = (bf16_t*)((char*)d_ws + 512 * 1024);         // 128 KB

    prep_mc<<<256, 256, 0, stream>>>(Bm, C, mc);
    pack_u<<<128, 64, 0, stream>>>(U, up);
    xu_gemm<<<2048, 256, 0, stream>>>(x, up, bias, out);
    scan_kernel<<<64, 512, 0, stream>>>(mc, out);
}

// Round 2
// 3373.719 us; speedup vs baseline: 2.3668x; 2.3668x over previous
//
#include <hip/hip_runtime.h>

#define EPS 0.01f
#define TSTEPS 2048
#define BATCH 64

typedef _Float16 half8 __attribute__((ext_vector_type(8)));
typedef _Float16 half4 __attribute__((ext_vector_type(4)));
typedef float f32x4 __attribute__((ext_vector_type(4)));

// ---------------------------------------------------------------------------
// prep_mc_pack: build Mc^T directly as f16 MFMA A-operand fragments.
// Scan wave w, M-tile mt (0..3 = A-matrix cols, 4..7 = W-matrix cols, same
// col range 64w+16*(mt&3)..+15), K-step kk.  A-frag layout (verified R1):
// lane l holds A[m=l&15][k=kk*32+(l>>4)*8+j], j=0..7.
// Here A-operand element (c, k) = Mat[k][c] (Mat = A or W),
//   A = B - 0.6*B^T - 0.01*I,  W = C - 0.6*C^T - 0.01*I.
// frag id f = (w*8+mt)*8+kk; out[(f*64+lane)*8+j].
// ---------------------------------------------------------------------------
__global__ void prep_mc_pack(const float* __restrict__ Bm, const float* __restrict__ Cm,
                             _Float16* __restrict__ mcPack) {
    int f = blockIdx.x;       // 0..255
    int lane = threadIdx.x;   // 0..63
    int w = f >> 6;
    int mt = (f >> 3) & 7;
    int kk = f & 7;
    const float* Src = (mt < 4) ? Bm : Cm;
    int c = 64 * w + 16 * (mt & 3) + (lane & 15);
    int k0 = kk * 32 + (lane >> 4) * 8;
    long off = ((long)f * 64 + lane) * 8;
#pragma unroll
    for (int j = 0; j < 8; ++j) {
        int k = k0 + j;
        float diag = (k == c) ? 0.01f : 0.0f;
        float v = Src[(long)k * 256 + c] - 0.6f * Src[(long)c * 256 + k] - diag;
        mcPack[off + j] = (_Float16)v;
    }
}

// ---------------------------------------------------------------------------
// pack_u: U (256x256 fp32) -> f16 B-operand fragments for xu_gemm.
// ---------------------------------------------------------------------------
__global__ void pack_u(const float* __restrict__ U, _Float16* __restrict__ up) {
    int t = blockIdx.x * 64 + threadIdx.x;
    int lane = t & 63;
    int tile = t >> 6;      // kk*16 + nn
    int nn = tile & 15;
    int kk = tile >> 4;
    int krow = kk * 32 + (lane >> 4) * 8;
    int col = nn * 16 + (lane & 15);
    long off = (long)t * 8;
#pragma unroll
    for (int jj = 0; jj < 8; ++jj) {
        up[off + jj] = (_Float16)U[(krow + jj) * 256 + col];
    }
}

// ---------------------------------------------------------------------------
// xu_gemm: out[r][n] = sum_k x[r][k]*U[k][n] + bias[n]  (f16 MFMA, fp32 out)
// Writes into d_out; scan overwrites in place with h.
// ---------------------------------------------------------------------------
__global__ __launch_bounds__(256) void xu_gemm(const float* __restrict__ x,
                                               const _Float16* __restrict__ up,
                                               const float* __restrict__ bias,
                                               float* __restrict__ out) {
    int wave = threadIdx.x >> 6;
    int lane = threadIdx.x & 63;
    int m = lane & 15;
    int quad = lane >> 4;
    long row0 = (long)blockIdx.x * 64 + wave * 16;
    const float* xrow = x + (row0 + m) * 256 + quad * 8;

    f32x4 acc[16];
#pragma unroll
    for (int nn = 0; nn < 16; ++nn) acc[nn] = (f32x4){0.f, 0.f, 0.f, 0.f};

#pragma unroll
    for (int kk = 0; kk < 8; ++kk) {
        f32x4 xa = *(const f32x4*)(xrow + kk * 32);
        f32x4 xb = *(const f32x4*)(xrow + kk * 32 + 4);
        half8 af;
        af[0] = (_Float16)xa[0]; af[1] = (_Float16)xa[1];
        af[2] = (_Float16)xa[2]; af[3] = (_Float16)xa[3];
        af[4] = (_Float16)xb[0]; af[5] = (_Float16)xb[1];
        af[6] = (_Float16)xb[2]; af[7] = (_Float16)xb[3];
        const _Float16* ub = up + ((long)kk * 1024 + lane) * 8;
#pragma unroll
        for (int nn = 0; nn < 16; ++nn) {
            half8 bf = *(const half8*)(ub + (long)nn * 512);
            acc[nn] = __builtin_amdgcn_mfma_f32_16x16x32_f16(af, bf, acc[nn], 0, 0, 0);
        }
    }
#pragma unroll
    for (int nn = 0; nn < 16; ++nn) {
        int col = nn * 16 + m;
        float bv = bias[col];
#pragma unroll
        for (int i = 0; i < 4; ++i) {
            out[(row0 + quad * 4 + i) * 256 + col] = acc[nn][i] + bv;
        }
    }
}

// ---------------------------------------------------------------------------
// scan_kernel: grid=4 (16 batch rows each), 256 threads (4 waves), 1 wave/SIMD.
// Per step: D' = Mc^T @ h^T via MFMA (Mc^T stationary in 256 VGPRs/lane),
// elementwise update in registers, h_new -> f16 B-frags in LDS (double buf).
// Wave w owns cols 64w..64w+63 of BOTH A (acc[0..3]) and W (acc[4..7]).
// C-layout: batch m = lane&15, col c = 64w+16mt+quad*4+i.
// hB element (n=batch, k): f16 idx = 256*(k>>3) + (k&7) + 8*n  [*2 bytes]
//   -> read (lane l, kk): idx = kk*512 + l*8 (contiguous 16B, conflict-free)
//   -> write (lane, mt):  idx = 1024w+256mt + 8m + 128*(q>>1) + 4*(q&1)
// ---------------------------------------------------------------------------
__global__ __launch_bounds__(256, 1) void scan_kernel(const _Float16* __restrict__ mcPack,
                                                      float* __restrict__ io) {
    const int tid = threadIdx.x;
    const int w = tid >> 6;
    const int lane = tid & 63;
    const int m = lane & 15;
    const int q = lane >> 4;
    const int b0 = blockIdx.x * 16;

    // Stationary A-operand fragments: 8 M-tiles x 8 K-steps = 256 VGPRs/lane.
    half8 mcf[8][8];
#pragma unroll
    for (int mt = 0; mt < 8; ++mt)
#pragma unroll
        for (int kk = 0; kk < 8; ++kk)
            mcf[mt][kk] = *(const half8*)(mcPack + (((long)(w * 8 + mt) * 8 + kk) * 64 + lane) * 8);

    __shared__ _Float16 hB[2][4096];  // 2 x 8KB double buffer, h^T as B-frags

    // zero buffer 0 (h0 = 0)
    {
        half8 z = (half8)(_Float16)0.0f;
        *(half8*)(&hB[0][tid * 16]) = z;
        *(half8*)(&hB[0][tid * 16 + 8]) = z;
    }

    const int rdIdx = lane * 8;
    const int wrIdx = 1024 * w + 8 * m + 128 * (q >> 1) + 4 * (q & 1);

    // per-lane global pointer: row b0+m, col 64w+4q; +16*mt handled by imm.
    float* p = io + ((long)(b0 + m) * TSTEPS) * 256 + 64 * w + 4 * q;

    f32x4 hrow[4];
#pragma unroll
    for (int mt = 0; mt < 4; ++mt) hrow[mt] = (f32x4){0.f, 0.f, 0.f, 0.f};

    f32x4 xq[2][4];
#pragma unroll
    for (int mt = 0; mt < 4; ++mt) {
        xq[0][mt] = *(const f32x4*)(p + mt * 16);
        xq[1][mt] = *(const f32x4*)(p + 256 + mt * 16);
    }
    __syncthreads();

    auto step = [&](int t, const _Float16* hbR, _Float16* hbW, f32x4 (&xc)[4]) {
        // ---- MFMA phase: read h B-frags, 64 MFMAs ----
        half8 hb[8];
#pragma unroll
        for (int kk = 0; kk < 8; ++kk)
            hb[kk] = *(const half8*)(hbR + kk * 512 + rdIdx);

        f32x4 acc[8];
#pragma unroll
        for (int mt = 0; mt < 8; ++mt) {
            acc[mt] = __builtin_amdgcn_mfma_f32_16x16x32_f16(mcf[mt][0], hb[0],
                                                             (f32x4){0.f, 0.f, 0.f, 0.f}, 0, 0, 0);
        }
#pragma unroll
        for (int kk = 1; kk < 8; ++kk)
#pragma unroll
            for (int mt = 0; mt < 8; ++mt)
                acc[mt] = __builtin_amdgcn_mfma_f32_16x16x32_f16(mcf[mt][kk], hb[kk], acc[mt], 0, 0, 0);

        // ---- elementwise: h += EPS*oa + EPS*tanh(ow + xu), all in regs ----
#pragma unroll
        for (int mt = 0; mt < 4; ++mt) {
            f32x4 oa = acc[mt];
            f32x4 ow = acc[mt + 4];
            f32x4 xv = xc[mt];
            f32x4 hn;
#pragma unroll
            for (int i = 0; i < 4; ++i) {
                float arg = ow[i] + xv[i];
                // tanh(x) = 1 - 2/(1+e^{2x});  e^{2x} = 2^{x*2*log2(e)}
                float e = __builtin_amdgcn_exp2f(arg * 2.8853900817779268f);
                float r = __builtin_amdgcn_rcpf(e + 1.0f);
                float th = fmaf(-2.0f, r, 1.0f);
                float v = fmaf(EPS, oa[i], hrow[mt][i]);
                hn[i] = fmaf(EPS, th, v);
            }
            hrow[mt] = hn;
            *(f32x4*)(p + mt * 16) = hn;             // h_t -> global out (in place)
            half4 h4;
#pragma unroll
            for (int i = 0; i < 4; ++i) h4[i] = (_Float16)hn[i];
            *(half4*)(hbW + wrIdx + mt * 256) = h4;  // next-step B-frags
        }

        // ---- prefetch xu[t+2] ----
        if (t + 2 < TSTEPS) {
#pragma unroll
            for (int mt = 0; mt < 4; ++mt)
                xc[mt] = *(const f32x4*)(p + 512 + mt * 16);
        }
        p += 256;
        __syncthreads();
    };

    for (int t = 0; t < TSTEPS; t += 2) {
        step(t, hB[0], hB[1], xq[0]);
        step(t + 1, hB[1], hB[0], xq[1]);
    }
}

extern "C" void kernel_launch(void* const* d_in, const int* in_sizes, int n_in,
                              void* d_out, int out_size, void* d_ws, size_t ws_size,
                              hipStream_t stream) {
    const float* x    = (const float*)d_in[0];
    const float* C    = (const float*)d_in[1];
    const float* Bm   = (const float*)d_in[2];
    const float* U    = (const float*)d_in[3];
    const float* bias = (const float*)d_in[4];
    float* out = (float*)d_out;

    _Float16* mcPack = (_Float16*)d_ws;                         // 256 KB
    _Float16* up     = (_Float16*)((char*)d_ws + 262144);       // 128 KB

    prep_mc_pack<<<256, 64, 0, stream>>>(Bm, C, mcPack);
    pack_u<<<128, 64, 0, stream>>>(U, up);
    xu_gemm<<<2048, 256, 0, stream>>>(x, up, bias, out);
    scan_kernel<<<4, 256, 0, stream>>>(mcPack, out);
}

// Round 3
// 3333.442 us; speedup vs baseline: 2.3954x; 1.0121x over previous
//
#include <hip/hip_runtime.h>

#define EPS 0.01f
#define TSTEPS 2048
#define BATCH 64

typedef _Float16 half8 __attribute__((ext_vector_type(8)));
typedef _Float16 half4 __attribute__((ext_vector_type(4)));
typedef float f32x4 __attribute__((ext_vector_type(4)));

// Workgroup barrier WITHOUT the vmcnt(0) drain the compiler emits for
// __syncthreads(). LDS visibility needs lgkmcnt(0) only; global loads
// (xu prefetch) and stores (h writeback) are lane-private and stay in
// flight across the barrier (AITER-style fine-grained pipelining).
#define LDS_BARRIER() asm volatile("s_waitcnt lgkmcnt(0)\n\ts_barrier" ::: "memory")

// ---------------------------------------------------------------------------
// prep_mc_pack: build Mc^T directly as f16 MFMA A-operand fragments.
// A-frag layout: lane l holds A[m=l&15][k=kk*32+(l>>4)*8+j], j=0..7.
// A-operand element (c, k) = Mat[k][c], Mat = B-0.6B^T-0.01I (mt<4) or
// C-0.6C^T-0.01I (mt>=4).  frag id f = (w*8+mt)*8+kk.
// ---------------------------------------------------------------------------
__global__ void prep_mc_pack(const float* __restrict__ Bm, const float* __restrict__ Cm,
                             _Float16* __restrict__ mcPack) {
    int f = blockIdx.x;       // 0..255
    int lane = threadIdx.x;   // 0..63
    int w = f >> 6;
    int mt = (f >> 3) & 7;
    int kk = f & 7;
    const float* Src = (mt < 4) ? Bm : Cm;
    int c = 64 * w + 16 * (mt & 3) + (lane & 15);
    int k0 = kk * 32 + (lane >> 4) * 8;
    long off = ((long)f * 64 + lane) * 8;
#pragma unroll
    for (int j = 0; j < 8; ++j) {
        int k = k0 + j;
        float diag = (k == c) ? 0.01f : 0.0f;
        float v = Src[(long)k * 256 + c] - 0.6f * Src[(long)c * 256 + k] - diag;
        mcPack[off + j] = (_Float16)v;
    }
}

// ---------------------------------------------------------------------------
// pack_u: U (256x256 fp32) -> f16 B-operand fragments for xu_gemm.
// ---------------------------------------------------------------------------
__global__ void pack_u(const float* __restrict__ U, _Float16* __restrict__ up) {
    int t = blockIdx.x * 64 + threadIdx.x;
    int lane = t & 63;
    int tile = t >> 6;      // kk*16 + nn
    int nn = tile & 15;
    int kk = tile >> 4;
    int krow = kk * 32 + (lane >> 4) * 8;
    int col = nn * 16 + (lane & 15);
    long off = (long)t * 8;
#pragma unroll
    for (int jj = 0; jj < 8; ++jj) {
        up[off + jj] = (_Float16)U[(krow + jj) * 256 + col];
    }
}

// ---------------------------------------------------------------------------
// xu_gemm: out[r][n] = sum_k x[r][k]*U[k][n] + bias[n]  (f16 MFMA, fp32 out)
// Writes into d_out; scan overwrites in place with h.
// ---------------------------------------------------------------------------
__global__ __launch_bounds__(256) void xu_gemm(const float* __restrict__ x,
                                               const _Float16* __restrict__ up,
                                               const float* __restrict__ bias,
                                               float* __restrict__ out) {
    int wave = threadIdx.x >> 6;
    int lane = threadIdx.x & 63;
    int m = lane & 15;
    int quad = lane >> 4;
    long row0 = (long)blockIdx.x * 64 + wave * 16;
    const float* xrow = x + (row0 + m) * 256 + quad * 8;

    f32x4 acc[16];
#pragma unroll
    for (int nn = 0; nn < 16; ++nn) acc[nn] = (f32x4){0.f, 0.f, 0.f, 0.f};

#pragma unroll
    for (int kk = 0; kk < 8; ++kk) {
        f32x4 xa = *(const f32x4*)(xrow + kk * 32);
        f32x4 xb = *(const f32x4*)(xrow + kk * 32 + 4);
        half8 af;
        af[0] = (_Float16)xa[0]; af[1] = (_Float16)xa[1];
        af[2] = (_Float16)xa[2]; af[3] = (_Float16)xa[3];
        af[4] = (_Float16)xb[0]; af[5] = (_Float16)xb[1];
        af[6] = (_Float16)xb[2]; af[7] = (_Float16)xb[3];
        const _Float16* ub = up + ((long)kk * 1024 + lane) * 8;
#pragma unroll
        for (int nn = 0; nn < 16; ++nn) {
            half8 bf = *(const half8*)(ub + (long)nn * 512);
            acc[nn] = __builtin_amdgcn_mfma_f32_16x16x32_f16(af, bf, acc[nn], 0, 0, 0);
        }
    }
#pragma unroll
    for (int nn = 0; nn < 16; ++nn) {
        int col = nn * 16 + m;
        float bv = bias[col];
#pragma unroll
        for (int i = 0; i < 4; ++i) {
            out[(row0 + quad * 4 + i) * 256 + col] = acc[nn][i] + bv;
        }
    }
}

// ---------------------------------------------------------------------------
// scan_kernel: grid=4 (16 batch rows each), 256 threads (4 waves), 1 wave/SIMD.
// Mc^T stationary in AGPRs (8x8 half8 frags/lane); h double-buffered in LDS
// as f16 B-frags; elementwise update in registers; xu read in-place from
// d_out (2-step prefetch) and overwritten with h_t.
// ---------------------------------------------------------------------------
__global__ __launch_bounds__(256, 1) void scan_kernel(const _Float16* __restrict__ mcPack,
                                                      float* __restrict__ io) {
    const int tid = threadIdx.x;
    const int w = tid >> 6;
    const int lane = tid & 63;
    const int m = lane & 15;
    const int q = lane >> 4;
    const int b0 = blockIdx.x * 16;

    // Stationary A-operand fragments: 8 M-tiles x 8 K-steps = 256 regs/lane.
    half8 mcf[8][8];
#pragma unroll
    for (int mt = 0; mt < 8; ++mt)
#pragma unroll
        for (int kk = 0; kk < 8; ++kk)
            mcf[mt][kk] = *(const half8*)(mcPack + (((long)(w * 8 + mt) * 8 + kk) * 64 + lane) * 8);

    __shared__ _Float16 hB[2][4096];  // 2 x 8KB double buffer, h^T as B-frags

    // zero buffer 0 (h0 = 0)
    {
        half8 z = (half8)(_Float16)0.0f;
        *(half8*)(&hB[0][tid * 16]) = z;
        *(half8*)(&hB[0][tid * 16 + 8]) = z;
    }

    const int rdIdx = lane * 8;
    const int wrIdx = 1024 * w + 8 * m + 128 * (q >> 1) + 4 * (q & 1);

    // per-lane global pointer: row b0+m, col 64w+4q; +16*mt via imm offset.
    float* p = io + ((long)(b0 + m) * TSTEPS) * 256 + 64 * w + 4 * q;

    f32x4 hrow[4];
#pragma unroll
    for (int mt = 0; mt < 4; ++mt) hrow[mt] = (f32x4){0.f, 0.f, 0.f, 0.f};

    f32x4 xq[2][4];
#pragma unroll
    for (int mt = 0; mt < 4; ++mt) {
        xq[0][mt] = *(const f32x4*)(p + mt * 16);
        xq[1][mt] = *(const f32x4*)(p + 256 + mt * 16);
    }
    __syncthreads();

    auto step = [&](int t, const _Float16* hbR, _Float16* hbW, f32x4 (&xc)[4]) {
        // ---- MFMA phase: read h B-frags, 64 MFMAs ----
        half8 hb[8];
#pragma unroll
        for (int kk = 0; kk < 8; ++kk)
            hb[kk] = *(const half8*)(hbR + kk * 512 + rdIdx);

        f32x4 acc[8];
#pragma unroll
        for (int mt = 0; mt < 8; ++mt) {
            acc[mt] = __builtin_amdgcn_mfma_f32_16x16x32_f16(mcf[mt][0], hb[0],
                                                             (f32x4){0.f, 0.f, 0.f, 0.f}, 0, 0, 0);
        }
#pragma unroll
        for (int kk = 1; kk < 8; ++kk)
#pragma unroll
            for (int mt = 0; mt < 8; ++mt)
                acc[mt] = __builtin_amdgcn_mfma_f32_16x16x32_f16(mcf[mt][kk], hb[kk], acc[mt], 0, 0, 0);

        // ---- elementwise: h += EPS*oa + EPS*tanh(ow + xu), all in regs ----
#pragma unroll
        for (int mt = 0; mt < 4; ++mt) {
            f32x4 oa = acc[mt];
            f32x4 ow = acc[mt + 4];
            f32x4 xv = xc[mt];
            f32x4 hn;
#pragma unroll
            for (int i = 0; i < 4; ++i) {
                float arg = ow[i] + xv[i];
                // tanh(x) = 1 - 2/(1+e^{2x});  e^{2x} = 2^{x*2*log2(e)}
                float e = __builtin_amdgcn_exp2f(arg * 2.8853900817779268f);
                float r = __builtin_amdgcn_rcpf(e + 1.0f);
                float th = fmaf(-2.0f, r, 1.0f);
                float v = fmaf(EPS, oa[i], hrow[mt][i]);
                hn[i] = fmaf(EPS, th, v);
            }
            hrow[mt] = hn;
            half4 h4;
#pragma unroll
            for (int i = 0; i < 4; ++i) h4[i] = (_Float16)hn[i];
            *(half4*)(hbW + wrIdx + mt * 256) = h4;  // next-step B-frags (LDS)
            *(f32x4*)(p + mt * 16) = hn;             // h_t -> global out (in place)
        }

        // ---- prefetch xu[t+2] (stays in flight across the barrier) ----
        if (t + 2 < TSTEPS) {
#pragma unroll
            for (int mt = 0; mt < 4; ++mt)
                xc[mt] = *(const f32x4*)(p + 512 + mt * 16);
        }
        p += 256;
        LDS_BARRIER();  // lgkmcnt(0)-only barrier: no vmcnt drain
    };

    for (int t = 0; t < TSTEPS; t += 2) {
        step(t, hB[0], hB[1], xq[0]);
        step(t + 1, hB[1], hB[0], xq[1]);
    }
}

extern "C" void kernel_launch(void* const* d_in, const int* in_sizes, int n_in,
                              void* d_out, int out_size, void* d_ws, size_t ws_size,
                              hipStream_t stream) {
    const float* x    = (const float*)d_in[0];
    const float* C    = (const float*)d_in[1];
    const float* Bm   = (const float*)d_in[2];
    const float* U    = (const float*)d_in[3];
    const float* bias = (const float*)d_in[4];
    float* out = (float*)d_out;

    _Float16* mcPack = (_Float16*)d_ws;                         // 256 KB
    _Float16* up     = (_Float16*)((char*)d_ws + 262144);       // 128 KB

    prep_mc_pack<<<256, 64, 0, stream>>>(Bm, C, mcPack);
    pack_u<<<128, 64, 0, stream>>>(U, up);
    xu_gemm<<<2048, 256, 0, stream>>>(x, up, bias, out);
    scan_kernel<<<4, 256, 0, stream>>>(mcPack, out);
}